// Round 1
// baseline (8785.506 us; speedup 1.0000x reference)
//
#include <hip/hip_runtime.h>

#define B_ 64
#define S_ 2048
#define I_ 512
#define H_ 512

typedef _Float16 half2v __attribute__((ext_vector_type(2)));
typedef _Float16 half8v __attribute__((ext_vector_type(8)));
typedef float    float4v __attribute__((ext_vector_type(4)));
typedef float    float2v __attribute__((ext_vector_type(2)));
typedef unsigned int uint4v __attribute__((ext_vector_type(4)));
typedef unsigned short ushort_t;

__device__ inline unsigned int pk2(float a, float b) {
    // v_cvt_pkrtz_f16_f32: pack (a->low, b->high)
    return __builtin_bit_cast(unsigned int, __builtin_amdgcn_cvt_pkrtz(a, b));
}

__device__ inline uint4v pack8(float4v a, float4v b) {
    uint4v r;
    r.x = pk2(a.x, a.y);
    r.y = pk2(a.z, a.w);
    r.z = pk2(b.x, b.y);
    r.w = pk2(b.z, b.w);
    return r;
}

__device__ inline float fdot2u(unsigned int h2, unsigned int w2, float acc) {
    return __builtin_amdgcn_fdot2(__builtin_bit_cast(half2v, h2),
                                  __builtin_bit_cast(half2v, w2), acc, false);
}

__device__ inline float fast_tanh(float y) {
    // tanh(y) = 1 - 2/(exp2(y*2*log2e) + 1); saturates correctly at +/-inf
    float e = __builtin_amdgcn_exp2f(y * 2.88539008f);
    return 1.f - 2.f * __builtin_amdgcn_rcpf(e + 1.f);
}

// VALU-pipe cross-lane add over the 16-lane DPP row (no LDS traffic).
// ctrl must be a literal: quad_perm xor1=0xB1, xor2=0x4E, row_ror:4=0x124,
// row_ror:8=0x128. After all 4 stages every lane of the row holds the row sum.
#define DPPADD(v, ctrl)                                                       \
    ((v) + __builtin_bit_cast(float, __builtin_amdgcn_update_dpp(             \
               0, __builtin_bit_cast(int, (v)), (ctrl), 0xf, 0xf, true)))

// ---------------------------------------------------------------------------
// Kernel 1: xp[m, n] = sum_k inputs[m, k] * W_ih[n, k] + b_ih[n]
// M = 131072, N = 512, K = 512.  Unchanged (verified, ~470 us).
// ---------------------------------------------------------------------------
__global__ __launch_bounds__(256, 2) void xproj_gemm(
    const float* __restrict__ A,    // [131072, 512] inputs
    const float* __restrict__ Bw,   // [512, 512]    W_ih
    const float* __restrict__ bias, // [512]         b_ih
    float* __restrict__ C)          // [131072, 512] -> d_out
{
    __shared__ uint4v As[64 * 5];
    __shared__ uint4v Bs[512 * 5];

    const int tid  = threadIdx.x;
    const int wave = tid >> 6;
    const int lane = tid & 63;
    const int lm   = lane & 15;
    const int lq   = lane >> 4;
    const int m0   = blockIdx.x * 64;
    const int nb   = wave * 128;

    float4v acc[4][8];
#pragma unroll
    for (int mf = 0; mf < 4; ++mf)
#pragma unroll
        for (int nf = 0; nf < 8; ++nf)
            acc[mf][nf] = (float4v){0.f, 0.f, 0.f, 0.f};

    float biasv[8];
#pragma unroll
    for (int nf = 0; nf < 8; ++nf)
        biasv[nf] = bias[nb + nf * 16 + lm];

    const int sm    = tid >> 2;
    const int skq   = tid & 3;
    const int sslot = skq ^ (sm & 3);

    for (int kt = 0; kt < 16; ++kt) {
        const int k0 = kt * 32;
        const float* ap = A + (size_t)(m0 + sm) * 512 + k0 + skq * 8;
        float4v a0 = *(const float4v*)ap;
        float4v a1 = *(const float4v*)(ap + 4);
        float4v b0[8], b1[8];
#pragma unroll
        for (int i = 0; i < 8; ++i) {
            const float* bp = Bw + (size_t)(sm + 64 * i) * 512 + k0 + skq * 8;
            b0[i] = *(const float4v*)bp;
            b1[i] = *(const float4v*)(bp + 4);
        }
        __syncthreads();
        As[sm * 5 + sslot] = pack8(a0, a1);
#pragma unroll
        for (int i = 0; i < 8; ++i)
            Bs[(sm + 64 * i) * 5 + sslot] = pack8(b0[i], b1[i]);
        __syncthreads();

        half8v af[4];
#pragma unroll
        for (int mf = 0; mf < 4; ++mf) {
            int row = mf * 16 + lm;
            af[mf] = __builtin_bit_cast(half8v, As[row * 5 + (lq ^ (lm & 3))]);
        }
        half8v bfr[8];
#pragma unroll
        for (int nf = 0; nf < 8; ++nf) {
            int row = nb + nf * 16 + lm;
            bfr[nf] = __builtin_bit_cast(half8v, Bs[row * 5 + (lq ^ (lm & 3))]);
        }
#pragma unroll
        for (int mf = 0; mf < 4; ++mf)
#pragma unroll
            for (int nf = 0; nf < 8; ++nf)
                acc[mf][nf] = __builtin_amdgcn_mfma_f32_16x16x32_f16(
                    af[mf], bfr[nf], acc[mf][nf], 0, 0, 0);
    }

#pragma unroll
    for (int mf = 0; mf < 4; ++mf) {
        int mrow = m0 + mf * 16 + lq * 4;
#pragma unroll
        for (int nf = 0; nf < 8; ++nf) {
            float* cp = C + (size_t)mrow * 512 + nb + nf * 16 + lm;
            float4v v = acc[mf][nf];
            cp[0]    = v.x + biasv[nf];
            cp[512]  = v.y + biasv[nf];
            cp[1024] = v.z + biasv[nf];
            cp[1536] = v.w + biasv[nf];
        }
    }
}

// ---------------------------------------------------------------------------
// Kernel 2 (REWRITTEN): sequential scan, lane-parallel h reads + DPP reduce.
//
// Old structure was LDS-issue-bound: 512 broadcast ds_read_b128/step/CU
// (~6100 of the 7440 cycles/step). New decomposition per wave (16 waves):
//   lane = jl*16 + kl   (jl = j-row 0..3, kl = k-lane 0..15)
//   outputs: j = w*32 + jl*8 + q, q = 0..7  (32 j per wave, 512 total)
//   k-slice per lane: k in { i*128 + kl*8 .. +8 | i=0..3 }  (32 k, 64 B)
// -> h read is 4 ds_read_b128/wave (64/CU vs 512), 16 distinct addrs,
//    4-way jl-broadcast, 2-way bank aliasing (free tier).
// -> W fragment wf[q][i] = 8 fp16, 128 regs/lane (same full residency).
// -> k-reduction: 4 DPP adds per output within the 16-lane row (VALU pipe,
//    quad_perm xor1/xor2 + row_ror:4/8; all lanes end with the row sum).
//    part[] LDS exchange + its barrier are gone: 1 barrier/step.
// -> owner lanes kl<4 handle the (2*kl, 2*kl+1) output pair: select via
//    loop-invariant cndmask tree, tanh, dwordx2 store, pk2 -> ds_write_b32
//    (16 consecutive LDS words, conflict-free), xp prefetch 2 steps ahead
//    through parity registers (loop unrolled x2 so the vmcnt wait lands a
//    full step after issue; ~1800 cy slack > ~900 cy HBM latency).
// ---------------------------------------------------------------------------
__global__ __launch_bounds__(1024, 1) void rnn_scan(
    const float* __restrict__ h0,   // [64, 512]
    const float* __restrict__ Whh,  // [512, 512]
    const float* __restrict__ bhh,  // [512]
    float* __restrict__ out)        // [B*S*H + B*H]
{
    __shared__ uint4v stage0[64];   // h(even t) as packed fp16: chunk c = h[8c..8c+8)
    __shared__ uint4v stage1[64];   // h(odd t)

    const int tid   = threadIdx.x;
    const int w     = tid >> 6;     // wave 0..15
    const int lane  = tid & 63;
    const int jl    = lane >> 4;    // DPP row 0..3
    const int kl    = lane & 15;    // k-lane within row
    const int b     = blockIdx.x;
    const int wbase = w * 32;

    // --- W fragments: wf[q][i] = W[wbase+jl*8+q][i*128 + kl*8 .. +8], fp16 ---
    uint4v wf[8][4];
#pragma unroll
    for (int q = 0; q < 8; ++q) {
        const float* wp = Whh + (size_t)(wbase + jl * 8 + q) * 512 + kl * 8;
#pragma unroll
        for (int i = 0; i < 4; ++i) {
            float4v f0 = *(const float4v*)(wp + i * 128);
            float4v f1 = *(const float4v*)(wp + i * 128 + 4);
            wf[q][i] = pack8(f0, f1);
        }
    }

    float* outb = out + (size_t)b * S_ * H_;
    const int jj = wbase + jl * 8 + 2 * kl;   // owner pair base (valid for kl<4)

    float be = 0.f, bo = 0.f;
    float xeA = 0.f, xoA = 0.f, xeB = 0.f, xoB = 0.f;
    if (kl < 4) {
        be = bhh[jj];
        bo = bhh[jj + 1];
        float2v x0 = *(const float2v*)(outb + jj);        // xp t=0
        float2v x1 = *(const float2v*)(outb + H_ + jj);   // xp t=1
        xeA = x0.x; xoA = x0.y;
        xeB = x1.x; xoB = x1.y;
    }
    if (tid < 512)
        ((ushort_t*)stage0)[tid] = (ushort_t)pk2(h0[b * 512 + tid], 0.f);
    __syncthreads();

#define STEP(T, RBUF, WBUF, XE, XO)                                           \
    {                                                                         \
        uint4v hv0 = RBUF[kl];                                                \
        uint4v hv1 = RBUF[16 + kl];                                           \
        uint4v hv2 = RBUF[32 + kl];                                           \
        uint4v hv3 = RBUF[48 + kl];                                           \
        float acc[8];                                                         \
        _Pragma("unroll") for (int q = 0; q < 8; ++q) {                       \
            float a = 0.f;                                                    \
            a = fdot2u(hv0.x, wf[q][0].x, a);                                 \
            a = fdot2u(hv0.y, wf[q][0].y, a);                                 \
            a = fdot2u(hv0.z, wf[q][0].z, a);                                 \
            a = fdot2u(hv0.w, wf[q][0].w, a);                                 \
            a = fdot2u(hv1.x, wf[q][1].x, a);                                 \
            a = fdot2u(hv1.y, wf[q][1].y, a);                                 \
            a = fdot2u(hv1.z, wf[q][1].z, a);                                 \
            a = fdot2u(hv1.w, wf[q][1].w, a);                                 \
            a = fdot2u(hv2.x, wf[q][2].x, a);                                 \
            a = fdot2u(hv2.y, wf[q][2].y, a);                                 \
            a = fdot2u(hv2.z, wf[q][2].z, a);                                 \
            a = fdot2u(hv2.w, wf[q][2].w, a);                                 \
            a = fdot2u(hv3.x, wf[q][3].x, a);                                 \
            a = fdot2u(hv3.y, wf[q][3].y, a);                                 \
            a = fdot2u(hv3.z, wf[q][3].z, a);                                 \
            a = fdot2u(hv3.w, wf[q][3].w, a);                                 \
            acc[q] = a;                                                       \
        }                                                                     \
        _Pragma("unroll") for (int q = 0; q < 8; ++q) {                       \
            float v = acc[q];                                                 \
            v = DPPADD(v, 0xB1);   /* quad_perm [1,0,3,2]  (xor1) */          \
            v = DPPADD(v, 0x4E);   /* quad_perm [2,3,0,1]  (xor2) */          \
            v = DPPADD(v, 0x124);  /* row_ror:4 */                            \
            v = DPPADD(v, 0x128);  /* row_ror:8 */                            \
            acc[q] = v;                                                       \
        }                                                                     \
        if (kl < 4) {                                                         \
            float ea = (kl & 1) ? acc[2] : acc[0];                            \
            float eb = (kl & 1) ? acc[6] : acc[4];                            \
            float oa = (kl & 1) ? acc[3] : acc[1];                            \
            float ob = (kl & 1) ? acc[7] : acc[5];                            \
            float ye = (kl & 2) ? eb : ea;                                    \
            float yo = (kl & 2) ? ob : oa;                                    \
            ye = fast_tanh(ye + (XE) + be);                                   \
            yo = fast_tanh(yo + (XO) + bo);                                   \
            *(float2v*)(outb + (size_t)(T) * H_ + jj) = (float2v){ye, yo};    \
            ((unsigned int*)(WBUF))[jj >> 1] = pk2(ye, yo);                   \
            /* prefetch xp for T+2 (reads past batch end at T>=S_-2 land in  */\
            /* the next batch / tail region of out: in-bounds, discarded)    */\
            float2v xn = *(const float2v*)(outb + (size_t)((T) + 2) * H_ + jj);\
            (XE) = xn.x; (XO) = xn.y;                                         \
            if ((T) == S_ - 1)                                                \
                *(float2v*)(out + (size_t)B_ * S_ * H_ + b * H_ + jj) =       \
                    (float2v){ye, yo};                                        \
        }                                                                     \
        __syncthreads();                                                      \
    }

    for (int t = 0; t < S_; t += 2) {
        STEP(t,     stage0, stage1, xeA, xoA);
        STEP(t + 1, stage1, stage0, xeB, xoB);
    }
#undef STEP
}

extern "C" void kernel_launch(void* const* d_in, const int* in_sizes, int n_in,
                              void* d_out, int out_size, void* d_ws, size_t ws_size,
                              hipStream_t stream) {
    const float* inputs = (const float*)d_in[0];
    const float* h0     = (const float*)d_in[1];
    const float* W_ih   = (const float*)d_in[2];
    const float* W_hh   = (const float*)d_in[3];
    const float* b_ih   = (const float*)d_in[4];
    const float* b_hh   = (const float*)d_in[5];
    float* out = (float*)d_out;

    // 1) xp = inputs @ W_ih^T + b_ih  -> staged into d_out
    hipLaunchKernelGGL(xproj_gemm, dim3(131072 / 64), dim3(256), 0, stream,
                       inputs, W_ih, b_ih, out);
    // 2) sequential scan, overwrites xp slots with h, writes h_final tail
    hipLaunchKernelGGL(rnn_scan, dim3(B_), dim3(1024), 0, stream,
                       h0, W_hh, b_hh, out);
}